// Round 6
// baseline (332.986 us; speedup 1.0000x reference)
//
#include <hip/hip_runtime.h>
#include <hip/hip_bf16.h>
#include <cfloat>

#define HD 128

typedef float f32x4 __attribute__((ext_vector_type(4)));
typedef __bf16 bf16x8 __attribute__((ext_vector_type(8)));

// -------- Kernel 1: segment bounds (batch is sorted) + work-queue reset ----
__global__ void seg_bounds_kernel(const int* __restrict__ batch, int n, int nseg,
                                  int* __restrict__ seg_start, int* __restrict__ ctr) {
  int b = blockIdx.x * blockDim.x + threadIdx.x;
  if (b == 0) *ctr = 0;            // reset dynamic queue every launch
  if (b > nseg) return;
  if (b == nseg) { seg_start[b] = n; return; }
  int lo = 0, hi = n;
  while (lo < hi) {
    int mid = (lo + hi) >> 1;
    if (batch[mid] < b) lo = mid + 1; else hi = mid;
  }
  seg_start[b] = lo;
}

// -------- Kernel 2: FUSED gate-score + online softmax + pooling ------------
// One wave per segment, segments claimed from a global atomic queue
// (persistent grid: 512 blocks = exactly resident at 2 blocks/CU).
// Triple-buffered (hA/hB/hC), 3-unrolled, OVERRUN-SAFE tile loop:
//   - loads clamp the row to len-1 (a real segment row) -> no tail branches
//   - invalid lanes get weight 0; gm/tmax see only real rows -> stats exact.
// Score algebra: score = sumW2 - 2*sum(w2/(1+e^{2x})) (b2 cancels in softmax).

#define LOAD_TILE(BUF, T)                                                   \
  {                                                                         \
    const int nIt_ = (T) * 16 + lr;                                         \
    const size_t row_ = (size_t)s0 + (size_t)min(nIt_, lenm1);              \
    const float* hp_ = h + row_ * HD + 8 * kl;                              \
    _Pragma("unroll")                                                       \
    for (int kt = 0; kt < 4; ++kt) {                                        \
      *reinterpret_cast<float4*>(&BUF[8 * kt]) =                            \
          *reinterpret_cast<const float4*>(hp_ + 32 * kt);                  \
      *reinterpret_cast<float4*>(&BUF[8 * kt + 4]) =                        \
          *reinterpret_cast<const float4*>(hp_ + 32 * kt + 4);              \
    }                                                                       \
  }

#define PROC_TILE(BUF, T)                                                   \
  {                                                                         \
    const bool valid_ = ((T) * 16 + lr) < len;                              \
    bf16x8 a_[4];                                                           \
    _Pragma("unroll")                                                       \
    for (int kt = 0; kt < 4; ++kt)                                          \
      _Pragma("unroll")                                                     \
      for (int j = 0; j < 8; ++j) a_[kt][j] = (__bf16)BUF[8 * kt + j];      \
    /* opaque: keep B-frag reads inside the loop (anti-LICM) */             \
    asm volatile("" : "+v"(dsb[0]), "+v"(dsb[1]), "+v"(dsb[2]),             \
                      "+v"(dsb[3]));                                        \
    f32x4 macc_[8];                                                         \
    _Pragma("unroll")                                                       \
    for (int f = 0; f < 8; ++f) macc_[f] = (f32x4){0.f, 0.f, 0.f, 0.f};     \
    _Pragma("unroll")                                                       \
    for (int kt = 0; kt < 4; ++kt) {                                        \
      const char* bp_ = reinterpret_cast<const char*>(sWt) + dsb[kt];       \
      _Pragma("unroll")                                                     \
      for (int f = 0; f < 8; ++f) {                                         \
        const bf16x8 bfr_ =                                                 \
            *reinterpret_cast<const bf16x8*>(bp_ + f * 4096);               \
        macc_[f] =                                                          \
            __builtin_amdgcn_mfma_f32_16x16x32_bf16(a_[kt], bfr_, macc_[f], \
                                                    0, 0, 0);               \
      }                                                                     \
    }                                                                       \
    float p2_[4] = {0.f, 0.f, 0.f, 0.f};                                    \
    _Pragma("unroll")                                                       \
    for (int f = 0; f < 8; ++f) {                                           \
      _Pragma("unroll")                                                     \
      for (int r = 0; r < 4; ++r) {                                         \
        const float xe_ = fmaf(LOG2E2, macc_[f][r], b1s[f]);                \
        const float e_ = exp2f(xe_);                                        \
        const float t_ = __builtin_amdgcn_rcpf(1.f + e_);                   \
        p2_[r] = fmaf(t_, w2r[f], p2_[r]);                                  \
      }                                                                     \
    }                                                                       \
    _Pragma("unroll")                                                       \
    for (int r = 0; r < 4; ++r) {                                           \
      p2_[r] += __shfl_xor(p2_[r], 1, 16);                                  \
      p2_[r] += __shfl_xor(p2_[r], 2, 16);                                  \
      p2_[r] += __shfl_xor(p2_[r], 4, 16);                                  \
      p2_[r] += __shfl_xor(p2_[r], 8, 16);                                  \
    }                                                                       \
    const float minp_ = fminf(fminf(p2_[0], p2_[1]), fminf(p2_[2], p2_[3]));\
    float tmax_ = fmaf(-2.f, minp_, sumW2);                                 \
    tmax_ = fmaxf(tmax_, __shfl_xor(tmax_, 16, 64));                        \
    tmax_ = fmaxf(tmax_, __shfl_xor(tmax_, 32, 64));                        \
    const int rr_ = lr & 3;                                                 \
    const float psel_ =                                                     \
        rr_ == 0 ? p2_[0] : (rr_ == 1 ? p2_[1] : (rr_ == 2 ? p2_[2]         \
                                                            : p2_[3]));     \
    const float vsc_ = fmaf(-2.f, psel_, sumW2);                            \
    const float sc_ = __shfl(vsc_, ((lr >> 2) << 4) | (lr & 3), 64);        \
    if (tmax_ > m) {                                                        \
      const float scl_ = exp2f((m - tmax_) * LOG2E);                        \
      s *= scl_;                                                            \
      _Pragma("unroll")                                                     \
      for (int j = 0; j < 32; ++j) acc[j] *= scl_;                          \
      m = tmax_;                                                            \
    }                                                                       \
    const float w_ = valid_ ? exp2f((sc_ - m) * LOG2E) : 0.f;               \
    s += w_;                                                                \
    _Pragma("unroll")                                                       \
    for (int j = 0; j < 32; ++j) {                                          \
      acc[j] = fmaf(BUF[j], w_, acc[j]);                                    \
      gm[j] = fmaxf(gm[j], BUF[j]);                                         \
    }                                                                       \
  }

__global__ __launch_bounds__(256, 2) void fused_pool_kernel(
    const float* __restrict__ h, const float* __restrict__ w1,
    const float* __restrict__ b1, const float* __restrict__ w2,
    const int* __restrict__ seg_start, float* __restrict__ g, int B,
    int* __restrict__ ctr)
{
  __shared__ __bf16 sWt[HD * HD];  // W1^T bf16, XOR-swizzled 16B slots (32 KB)

  for (int i = threadIdx.x; i < HD * HD / 4; i += 256) {
    const int k = i >> 5;
    const int c4 = (i & 31) << 2;
    const float4 v = reinterpret_cast<const float4*>(w1)[i];
    const float vv[4] = {v.x, v.y, v.z, v.w};
#pragma unroll
    for (int q = 0; q < 4; ++q) {
      const int c = c4 + q;
      sWt[c * HD + ((((k >> 3) ^ (c & 15)) << 3) | (k & 7))] = (__bf16)vv[q];
    }
  }
  __syncthreads();

  const float LOG2E  = 1.44269504088896341f;
  const float LOG2E2 = 2.88539008177792681f;

  const int lane = threadIdx.x & 63;
  const int lr   = lane & 15;
  const int kl   = lane >> 4;

  float w2r[8], b1s[8];
#pragma unroll
  for (int f = 0; f < 8; ++f) {
    w2r[f] = w2[16 * f + lr];
    b1s[f] = LOG2E2 * b1[16 * f + lr];
  }
  float sumW2 = 0.f;
#pragma unroll
  for (int f = 0; f < 8; ++f) sumW2 += w2r[f];
  sumW2 += __shfl_xor(sumW2, 1, 16);
  sumW2 += __shfl_xor(sumW2, 2, 16);
  sumW2 += __shfl_xor(sumW2, 4, 16);
  sumW2 += __shfl_xor(sumW2, 8, 16);

  // Loop-invariant B-fragment LDS byte offsets: addr(kt,f) = dsb[kt] + f*4096.
  // (c & 15 == lr for every fragment column c = 16f + lr.)
  int dsb[4];
#pragma unroll
  for (int kt = 0; kt < 4; ++kt)
    dsb[kt] = lr * 256 + (((4 * kt + kl) ^ lr) << 4);

  for (;;) {
    int b;
    if (lane == 0) b = atomicAdd(ctr, 1);
    b = __shfl(b, 0, 64);
    if (b >= B) break;

    const int s0  = seg_start[b];
    const int len = seg_start[b + 1] - s0;
    const int lenm1 = len - 1;
    const int nt  = (len + 15) >> 4;

    float m = -FLT_MAX, s = 0.f;
    float acc[32], gm[32];
#pragma unroll
    for (int j = 0; j < 32; ++j) { acc[j] = 0.f; gm[j] = -FLT_MAX; }

    float hA[32], hB[32], hC[32];
    LOAD_TILE(hA, 0)
    LOAD_TILE(hB, 1)
    for (int t = 0; t < nt; t += 3) {
      LOAD_TILE(hC, t + 2)
      PROC_TILE(hA, t)
      LOAD_TILE(hA, t + 3)
      PROC_TILE(hB, t + 1)
      LOAD_TILE(hB, t + 4)
      PROC_TILE(hC, t + 2)
    }

    // reduce partials across the 16 lr lanes (features depend only on kl)
#pragma unroll
    for (int off = 1; off <= 8; off <<= 1) {
      s += __shfl_xor(s, off, 16);
#pragma unroll
      for (int j = 0; j < 32; ++j) {
        acc[j] += __shfl_xor(acc[j], off, 16);
        gm[j] = fmaxf(gm[j], __shfl_xor(gm[j], off, 16));
      }
    }

    if (lr == 0) {  // lanes 0,16,32,48: one per kl group
      const float invS = (s > 0.f) ? 1.f / s : 0.f;
#pragma unroll
      for (int kt = 0; kt < 4; ++kt) {
        const int fb = 32 * kt + 8 * kl;
        float4 va, vb, ma, mb;
        va.x = acc[8*kt+0]*invS; va.y = acc[8*kt+1]*invS;
        va.z = acc[8*kt+2]*invS; va.w = acc[8*kt+3]*invS;
        vb.x = acc[8*kt+4]*invS; vb.y = acc[8*kt+5]*invS;
        vb.z = acc[8*kt+6]*invS; vb.w = acc[8*kt+7]*invS;
        ma.x = gm[8*kt+0]; ma.y = gm[8*kt+1]; ma.z = gm[8*kt+2]; ma.w = gm[8*kt+3];
        mb.x = gm[8*kt+4]; mb.y = gm[8*kt+5]; mb.z = gm[8*kt+6]; mb.w = gm[8*kt+7];
        *reinterpret_cast<float4*>(&g[(size_t)b * 256 + fb])           = va;
        *reinterpret_cast<float4*>(&g[(size_t)b * 256 + fb + 4])       = vb;
        *reinterpret_cast<float4*>(&g[(size_t)b * 256 + 128 + fb])     = ma;
        *reinterpret_cast<float4*>(&g[(size_t)b * 256 + 128 + fb + 4]) = mb;
      }
    }
  }
}

// -------- Kernel 3: MLP head, 4 segments per block --------
__global__ __launch_bounds__(512) void mlp_kernel(
    const float* __restrict__ g, const float* __restrict__ w1,
    const float* __restrict__ b1, const float* __restrict__ w2,
    const float* __restrict__ b2, float* __restrict__ out)
{
  __shared__ float sg[4][256];
  __shared__ float sred[4][2];
  const int t = threadIdx.x;
  const int sidx = t >> 7;
  const int u = t & 127;
  const int b0 = blockIdx.x * 4;
  sg[sidx][u]       = g[(size_t)(b0 + sidx) * 256 + u];
  sg[sidx][u + 128] = g[(size_t)(b0 + sidx) * 256 + 128 + u];
  __syncthreads();
  float acc = b1[u];
#pragma unroll 8
  for (int k = 0; k < 256; ++k)
    acc = fmaf(sg[sidx][k], w1[k * HD + u], acc);
  float v = fmaxf(acc, 0.f) * w2[u];
#pragma unroll
  for (int off = 32; off >= 1; off >>= 1) v += __shfl_xor(v, off, 64);
  if ((t & 63) == 0) sred[sidx][(t >> 6) & 1] = v;
  __syncthreads();
  if (u == 0) out[b0 + sidx] = sred[sidx][0] + sred[sidx][1] + b2[0];
}

extern "C" void kernel_launch(void* const* d_in, const int* in_sizes, int n_in,
                              void* d_out, int out_size, void* d_ws, size_t ws_size,
                              hipStream_t stream) {
  const float* h       = (const float*)d_in[0];
  const int*   batch   = (const int*)d_in[1];
  const float* gate_w1 = (const float*)d_in[2];
  const float* gate_b1 = (const float*)d_in[3];
  const float* gate_w2 = (const float*)d_in[4];
  const float* mlp_w1  = (const float*)d_in[6];
  const float* mlp_b1  = (const float*)d_in[7];
  const float* mlp_w2  = (const float*)d_in[8];
  const float* mlp_b2  = (const float*)d_in[9];
  float* out = (float*)d_out;

  const int N = in_sizes[0] / HD;   // 1048576
  const int B = out_size;           // 4096

  char* ws = (char*)d_ws;
  float* g   = (float*)ws;                              // B*256 floats
  int*   seg = (int*)(ws + (size_t)B * 256 * 4);        // B+1 ints
  int*   ctr = seg + (B + 2);                           // work-queue counter

  seg_bounds_kernel<<<(B + 256) / 256, 256, 0, stream>>>(batch, N, B, seg, ctr);
  // Persistent: 512 blocks x 4 waves = 2048 waves, exactly resident at
  // 2 blocks/CU; segments claimed dynamically.
  fused_pool_kernel<<<512, 256, 0, stream>>>(h, gate_w1, gate_b1, gate_w2,
                                             seg, g, B, ctr);
  mlp_kernel<<<B / 4, 512, 0, stream>>>(g, mlp_w1, mlp_b1, mlp_w2, mlp_b2, out);
}

// Round 7
// 208.624 us; speedup vs baseline: 1.5961x; 1.5961x over previous
//
#include <hip/hip_runtime.h>
#include <hip/hip_bf16.h>
#include <cfloat>

#define HD 128

typedef float f32x4 __attribute__((ext_vector_type(4)));
typedef __bf16 bf16x8 __attribute__((ext_vector_type(8)));

// -------- Kernel 1: segment bounds (batch is sorted) + work-queue reset ----
__global__ void seg_bounds_kernel(const int* __restrict__ batch, int n, int nseg,
                                  int* __restrict__ seg_start, int* __restrict__ ctr) {
  int b = blockIdx.x * blockDim.x + threadIdx.x;
  if (b == 0) *ctr = 0;            // reset dynamic queue every launch
  if (b > nseg) return;
  if (b == nseg) { seg_start[b] = n; return; }
  int lo = 0, hi = n;
  while (lo < hi) {
    int mid = (lo + hi) >> 1;
    if (batch[mid] < b) lo = mid + 1; else hi = mid;
  }
  seg_start[b] = lo;
}

// -------- Kernel 2: FUSED gate-score + online softmax + pooling ------------
// One wave per segment, segments claimed from a global atomic queue
// (persistent grid: 512 blocks = exactly resident at 2 blocks/CU).
// DOUBLE-buffered (hA/hB — triple buffer spilled to scratch in R6),
// branch-free overrun-safe loop: loads clamp the row to len-1 (a real row),
// invalid lanes get weight 0, so extra PROCs are mathematical no-ops.
// Score algebra: score = sumW2 - 2*sum(w2/(1+e^{2x})) (b2 cancels in softmax).

#define LOAD_TILE(BUF, T)                                                   \
  {                                                                         \
    const int nIt_ = (T) * 16 + lr;                                         \
    const size_t row_ = (size_t)s0 + (size_t)min(nIt_, lenm1);              \
    const float* hp_ = h + row_ * HD + 8 * kl;                              \
    _Pragma("unroll")                                                       \
    for (int kt = 0; kt < 4; ++kt) {                                        \
      *reinterpret_cast<float4*>(&BUF[8 * kt]) =                            \
          *reinterpret_cast<const float4*>(hp_ + 32 * kt);                  \
      *reinterpret_cast<float4*>(&BUF[8 * kt + 4]) =                        \
          *reinterpret_cast<const float4*>(hp_ + 32 * kt + 4);              \
    }                                                                       \
  }

#define PROC_TILE(BUF, T)                                                   \
  {                                                                         \
    const bool valid_ = ((T) * 16 + lr) < len;                              \
    bf16x8 a_[4];                                                           \
    _Pragma("unroll")                                                       \
    for (int kt = 0; kt < 4; ++kt)                                          \
      _Pragma("unroll")                                                     \
      for (int j = 0; j < 8; ++j) a_[kt][j] = (__bf16)BUF[8 * kt + j];      \
    /* opaque: keep B-frag reads inside the loop (anti-LICM) */             \
    asm volatile("" : "+v"(dsb[0]), "+v"(dsb[1]), "+v"(dsb[2]),             \
                      "+v"(dsb[3]));                                        \
    f32x4 macc_[8];                                                         \
    _Pragma("unroll")                                                       \
    for (int f = 0; f < 8; ++f) macc_[f] = (f32x4){0.f, 0.f, 0.f, 0.f};     \
    _Pragma("unroll")                                                       \
    for (int kt = 0; kt < 4; ++kt) {                                        \
      const char* bp_ = reinterpret_cast<const char*>(sWt) + dsb[kt];       \
      _Pragma("unroll")                                                     \
      for (int f = 0; f < 8; ++f) {                                         \
        const bf16x8 bfr_ =                                                 \
            *reinterpret_cast<const bf16x8*>(bp_ + f * 4096);               \
        macc_[f] =                                                          \
            __builtin_amdgcn_mfma_f32_16x16x32_bf16(a_[kt], bfr_, macc_[f], \
                                                    0, 0, 0);               \
      }                                                                     \
    }                                                                       \
    float p2_[4] = {0.f, 0.f, 0.f, 0.f};                                    \
    _Pragma("unroll")                                                       \
    for (int f = 0; f < 8; ++f) {                                           \
      _Pragma("unroll")                                                     \
      for (int r = 0; r < 4; ++r) {                                         \
        const float xe_ = fmaf(LOG2E2, macc_[f][r], b1s[f]);                \
        const float e_ = exp2f(xe_);                                        \
        const float t_ = __builtin_amdgcn_rcpf(1.f + e_);                   \
        p2_[r] = fmaf(t_, w2r[f], p2_[r]);                                  \
      }                                                                     \
    }                                                                       \
    _Pragma("unroll")                                                       \
    for (int r = 0; r < 4; ++r) {                                           \
      p2_[r] += __shfl_xor(p2_[r], 1, 16);                                  \
      p2_[r] += __shfl_xor(p2_[r], 2, 16);                                  \
      p2_[r] += __shfl_xor(p2_[r], 4, 16);                                  \
      p2_[r] += __shfl_xor(p2_[r], 8, 16);                                  \
    }                                                                       \
    const float minp_ = fminf(fminf(p2_[0], p2_[1]), fminf(p2_[2], p2_[3]));\
    float tmax_ = fmaf(-2.f, minp_, sumW2);                                 \
    tmax_ = fmaxf(tmax_, __shfl_xor(tmax_, 16, 64));                        \
    tmax_ = fmaxf(tmax_, __shfl_xor(tmax_, 32, 64));                        \
    const int rr_ = lr & 3;                                                 \
    const float psel_ =                                                     \
        rr_ == 0 ? p2_[0] : (rr_ == 1 ? p2_[1] : (rr_ == 2 ? p2_[2]         \
                                                            : p2_[3]));     \
    const float vsc_ = fmaf(-2.f, psel_, sumW2);                            \
    const float sc_ = __shfl(vsc_, ((lr >> 2) << 4) | (lr & 3), 64);        \
    if (tmax_ > m) {                                                        \
      const float scl_ = exp2f((m - tmax_) * LOG2E);                        \
      s *= scl_;                                                            \
      _Pragma("unroll")                                                     \
      for (int j = 0; j < 32; ++j) acc[j] *= scl_;                          \
      m = tmax_;                                                            \
    }                                                                       \
    const float w_ = valid_ ? exp2f((sc_ - m) * LOG2E) : 0.f;               \
    s += w_;                                                                \
    _Pragma("unroll")                                                       \
    for (int j = 0; j < 32; ++j) {                                          \
      acc[j] = fmaf(BUF[j], w_, acc[j]);                                    \
      gm[j] = fmaxf(gm[j], BUF[j]);                                         \
    }                                                                       \
  }

__global__ __launch_bounds__(256, 2) void fused_pool_kernel(
    const float* __restrict__ h, const float* __restrict__ w1,
    const float* __restrict__ b1, const float* __restrict__ w2,
    const int* __restrict__ seg_start, float* __restrict__ g, int B,
    int* __restrict__ ctr)
{
  __shared__ __bf16 sWt[HD * HD];  // W1^T bf16, XOR-swizzled 16B slots (32 KB)

  for (int i = threadIdx.x; i < HD * HD / 4; i += 256) {
    const int k = i >> 5;
    const int c4 = (i & 31) << 2;
    const float4 v = reinterpret_cast<const float4*>(w1)[i];
    const float vv[4] = {v.x, v.y, v.z, v.w};
#pragma unroll
    for (int q = 0; q < 4; ++q) {
      const int c = c4 + q;
      sWt[c * HD + ((((k >> 3) ^ (c & 15)) << 3) | (k & 7))] = (__bf16)vv[q];
    }
  }
  __syncthreads();

  const float LOG2E  = 1.44269504088896341f;
  const float LOG2E2 = 2.88539008177792681f;

  const int lane = threadIdx.x & 63;
  const int lr   = lane & 15;
  const int kl   = lane >> 4;

  float w2r[8], b1s[8];
#pragma unroll
  for (int f = 0; f < 8; ++f) {
    w2r[f] = w2[16 * f + lr];
    b1s[f] = LOG2E2 * b1[16 * f + lr];
  }
  float sumW2 = 0.f;
#pragma unroll
  for (int f = 0; f < 8; ++f) sumW2 += w2r[f];
  sumW2 += __shfl_xor(sumW2, 1, 16);
  sumW2 += __shfl_xor(sumW2, 2, 16);
  sumW2 += __shfl_xor(sumW2, 4, 16);
  sumW2 += __shfl_xor(sumW2, 8, 16);

  // Loop-invariant B-fragment LDS byte offsets: addr(kt,f) = dsb[kt] + f*4096.
  // (c & 15 == lr for every fragment column c = 16f + lr.)
  int dsb[4];
#pragma unroll
  for (int kt = 0; kt < 4; ++kt)
    dsb[kt] = lr * 256 + (((4 * kt + kl) ^ lr) << 4);

  for (;;) {
    int b;
    if (lane == 0) b = atomicAdd(ctr, 1);
    b = __shfl(b, 0, 64);
    if (b >= B) break;

    const int s0  = seg_start[b];
    const int len = seg_start[b + 1] - s0;
    const int lenm1 = len - 1;
    const int nt  = (len + 15) >> 4;

    float m = -FLT_MAX, s = 0.f;
    float acc[32], gm[32];
#pragma unroll
    for (int j = 0; j < 32; ++j) { acc[j] = 0.f; gm[j] = -FLT_MAX; }

    if (nt > 0) {
      float hA[32], hB[32];
      LOAD_TILE(hA, 0)
      LOAD_TILE(hB, 1)
      for (int t = 0; t < nt; t += 2) {
        PROC_TILE(hA, t)
        LOAD_TILE(hA, t + 2)
        PROC_TILE(hB, t + 1)
        LOAD_TILE(hB, t + 3)
      }
    }

    // reduce partials across the 16 lr lanes (features depend only on kl)
#pragma unroll
    for (int off = 1; off <= 8; off <<= 1) {
      s += __shfl_xor(s, off, 16);
#pragma unroll
      for (int j = 0; j < 32; ++j) {
        acc[j] += __shfl_xor(acc[j], off, 16);
        gm[j] = fmaxf(gm[j], __shfl_xor(gm[j], off, 16));
      }
    }

    if (lr == 0) {  // lanes 0,16,32,48: one per kl group
      const float invS = (s > 0.f) ? 1.f / s : 0.f;
#pragma unroll
      for (int kt = 0; kt < 4; ++kt) {
        const int fb = 32 * kt + 8 * kl;
        float4 va, vb, ma, mb;
        va.x = acc[8*kt+0]*invS; va.y = acc[8*kt+1]*invS;
        va.z = acc[8*kt+2]*invS; va.w = acc[8*kt+3]*invS;
        vb.x = acc[8*kt+4]*invS; vb.y = acc[8*kt+5]*invS;
        vb.z = acc[8*kt+6]*invS; vb.w = acc[8*kt+7]*invS;
        ma.x = gm[8*kt+0]; ma.y = gm[8*kt+1]; ma.z = gm[8*kt+2]; ma.w = gm[8*kt+3];
        mb.x = gm[8*kt+4]; mb.y = gm[8*kt+5]; mb.z = gm[8*kt+6]; mb.w = gm[8*kt+7];
        *reinterpret_cast<float4*>(&g[(size_t)b * 256 + fb])           = va;
        *reinterpret_cast<float4*>(&g[(size_t)b * 256 + fb + 4])       = vb;
        *reinterpret_cast<float4*>(&g[(size_t)b * 256 + 128 + fb])     = ma;
        *reinterpret_cast<float4*>(&g[(size_t)b * 256 + 128 + fb + 4]) = mb;
      }
    }
  }
}

// -------- Kernel 3: MLP head, 4 segments per block --------
__global__ __launch_bounds__(512) void mlp_kernel(
    const float* __restrict__ g, const float* __restrict__ w1,
    const float* __restrict__ b1, const float* __restrict__ w2,
    const float* __restrict__ b2, float* __restrict__ out)
{
  __shared__ float sg[4][256];
  __shared__ float sred[4][2];
  const int t = threadIdx.x;
  const int sidx = t >> 7;
  const int u = t & 127;
  const int b0 = blockIdx.x * 4;
  sg[sidx][u]       = g[(size_t)(b0 + sidx) * 256 + u];
  sg[sidx][u + 128] = g[(size_t)(b0 + sidx) * 256 + 128 + u];
  __syncthreads();
  float acc = b1[u];
#pragma unroll 8
  for (int k = 0; k < 256; ++k)
    acc = fmaf(sg[sidx][k], w1[k * HD + u], acc);
  float v = fmaxf(acc, 0.f) * w2[u];
#pragma unroll
  for (int off = 32; off >= 1; off >>= 1) v += __shfl_xor(v, off, 64);
  if ((t & 63) == 0) sred[sidx][(t >> 6) & 1] = v;
  __syncthreads();
  if (u == 0) out[b0 + sidx] = sred[sidx][0] + sred[sidx][1] + b2[0];
}

extern "C" void kernel_launch(void* const* d_in, const int* in_sizes, int n_in,
                              void* d_out, int out_size, void* d_ws, size_t ws_size,
                              hipStream_t stream) {
  const float* h       = (const float*)d_in[0];
  const int*   batch   = (const int*)d_in[1];
  const float* gate_w1 = (const float*)d_in[2];
  const float* gate_b1 = (const float*)d_in[3];
  const float* gate_w2 = (const float*)d_in[4];
  const float* mlp_w1  = (const float*)d_in[6];
  const float* mlp_b1  = (const float*)d_in[7];
  const float* mlp_w2  = (const float*)d_in[8];
  const float* mlp_b2  = (const float*)d_in[9];
  float* out = (float*)d_out;

  const int N = in_sizes[0] / HD;   // 1048576
  const int B = out_size;           // 4096

  char* ws = (char*)d_ws;
  float* g   = (float*)ws;                              // B*256 floats
  int*   seg = (int*)(ws + (size_t)B * 256 * 4);        // B+1 ints
  int*   ctr = seg + (B + 2);                           // work-queue counter

  seg_bounds_kernel<<<(B + 256) / 256, 256, 0, stream>>>(batch, N, B, seg, ctr);
  // Persistent: 512 blocks x 4 waves = 2048 waves, exactly resident at
  // 2 blocks/CU; segments claimed dynamically.
  fused_pool_kernel<<<512, 256, 0, stream>>>(h, gate_w1, gate_b1, gate_w2,
                                             seg, g, B, ctr);
  mlp_kernel<<<B / 4, 512, 0, stream>>>(g, mlp_w1, mlp_b1, mlp_w2, mlp_b2, out);
}